// Round 6
// baseline (1037.875 us; speedup 1.0000x reference)
//
#include <hip/hip_runtime.h>

// ---------------- problem constants ----------------
#define Q_   25600
#define C_   256
#define NH_  8
#define HD_  32
#define NP_  4
#define LC_  2
#define HW_  160          // H == W == 160

#define QC   (Q_ * C_)            // 6,553,600
#define VC   (2 * QC)             // 13,107,200
#define REFN (Q_ * LC_ * 2)       // 102,400

typedef unsigned short ushort_t;
typedef __attribute__((ext_vector_type(8))) short short8;
typedef __attribute__((ext_vector_type(4))) float f32x4;

// ---------------- bf16 helpers ----------------
__device__ __forceinline__ float b2f(ushort_t u) {
    union { unsigned int u32; float f; } c; c.u32 = ((unsigned int)u) << 16; return c.f;
}
__device__ __forceinline__ ushort_t f2b(float f) {
    union { float f; unsigned int u32; } c; c.f = f;
    unsigned int u = c.u32;
    return (ushort_t)((u + 0x7FFFu + ((u >> 16) & 1u)) >> 16);
}
__device__ __forceinline__ unsigned int pack2(float lo, float hi){
    return (unsigned int)f2b(lo) | ((unsigned int)f2b(hi) << 16);
}
__device__ __forceinline__ short8 pack8(float4 a, float4 b){
    union { short8 s; ushort_t u[8]; } r;
    r.u[0]=f2b(a.x); r.u[1]=f2b(a.y); r.u[2]=f2b(a.z); r.u[3]=f2b(a.w);
    r.u[4]=f2b(b.x); r.u[5]=f2b(b.y); r.u[6]=f2b(b.z); r.u[7]=f2b(b.w);
    return r.s;
}

// ---------------- prologue: qpq = bf16(query+qpos) + weight transposes (fp32->bf16) ----------------
struct TDesc { const float* src; ushort_t* dst; int K; int N; };
struct TAll  { TDesc t[10]; };

#define QC4   (QC / 4)        // 1,638,400
#define TRANS_TOTAL 860160
#define PRO_TOTAL (QC4 + TRANS_TOTAL)

__global__ __launch_bounds__(256) void prologue_kernel(
    const float* __restrict__ query, const float* __restrict__ qpos,
    ushort_t* __restrict__ qpq, TAll td)
{
    int i = blockIdx.x * 256 + threadIdx.x;
    if (i < QC4) {
        float4 qv = ((const float4*)query)[i];
        float4 pv = ((const float4*)qpos)[i];
        uint2 o;
        o.x = pack2(qv.x + pv.x, qv.y + pv.y);
        o.y = pack2(qv.z + pv.z, qv.w + pv.w);
        ((uint2*)qpq)[i] = o;
        return;
    }
    i -= QC4;
    #pragma unroll 1
    for (int m = 0; m < 10; m++) {
        int sz = td.t[m].K * td.t[m].N;
        if (i < sz) {
            int N = td.t[m].N, K = td.t[m].K;
            int k = i / N, n = i - k * N;
            td.t[m].dst[(size_t)n * K + k] = f2b(td.t[m].src[i]);
            return;
        }
        i -= sz;
    }
}

// ---------------- tiny: spatial_shapes int32 -> fp32 ----------------
__global__ void ss_kernel(const int* __restrict__ ss, float* __restrict__ out_ss)
{
    int i = threadIdx.x;
    if (i < 4) out_ss[i] = (float)ss[i];
}

// ---------------- MFMA GEMM ----------------
// C = A[M,K] @ B[K,N] + bias (+res) (+relu).  Bt = B^T [N,K] bf16.
// AF32: A operand read from fp32. RESM: 0 none, 1 bf16 res, 2 fp32 res.
// OSPLIT: 1 -> write C in head-split layout [L, NH, Q_, HD] (l=row/Q_, h=col>>5, d=col&31)
template<int WN, bool RELU, int RESM, bool AF32, int OSPLIT>
__global__ __launch_bounds__(256) void gemm_bf16(
    const ushort_t* __restrict__ A16, const float* __restrict__ A32,
    const ushort_t* __restrict__ Bt, const float* __restrict__ bias,
    const ushort_t* __restrict__ res16, const float* __restrict__ res32,
    ushort_t* __restrict__ Cout, int M, int N, int K)
{
    const int lane = threadIdx.x & 63;
    const int wave = threadIdx.x >> 6;
    const int m0 = blockIdx.x * 256 + wave * 64;
    const int n0 = blockIdx.y * (16 * WN);
    const int r = lane & 15, quad = lane >> 4;

    f32x4 acc[4][WN];
    #pragma unroll
    for (int i = 0; i < 4; i++)
        #pragma unroll
        for (int j = 0; j < WN; j++) acc[i][j] = (f32x4){0.f, 0.f, 0.f, 0.f};

    const ushort_t* Ab16 = AF32 ? nullptr : (A16 + (size_t)(m0 + r) * K + quad * 8);
    const float*    Ab32 = AF32 ? (A32 + (size_t)(m0 + r) * K + quad * 8) : nullptr;
    const ushort_t* Bbase = Bt + (size_t)(n0 + r) * K + quad * 8;

    for (int k0 = 0; k0 < K; k0 += 32) {
        short8 af[4], bfr[WN];
        #pragma unroll
        for (int i = 0; i < 4; i++) {
            if (AF32) {
                float4 u = *(const float4*)(Ab32 + (size_t)i * 16 * K + k0);
                float4 v = *(const float4*)(Ab32 + (size_t)i * 16 * K + k0 + 4);
                af[i] = pack8(u, v);
            } else {
                af[i] = *(const short8*)(Ab16 + (size_t)i * 16 * K + k0);
            }
        }
        #pragma unroll
        for (int j = 0; j < WN; j++)
            bfr[j] = *(const short8*)(Bbase + (size_t)j * 16 * K + k0);
        #pragma unroll
        for (int i = 0; i < 4; i++)
            #pragma unroll
            for (int j = 0; j < WN; j++)
                acc[i][j] = __builtin_amdgcn_mfma_f32_16x16x32_bf16(af[i], bfr[j], acc[i][j], 0, 0, 0);
    }

    float bv[WN];
    #pragma unroll
    for (int j = 0; j < WN; j++) bv[j] = bias[n0 + j * 16 + r];

    #pragma unroll
    for (int i = 0; i < 4; i++) {
        int row0 = m0 + i * 16 + quad * 4;
        #pragma unroll
        for (int j = 0; j < WN; j++) {
            int col = n0 + j * 16 + r;
            #pragma unroll
            for (int t = 0; t < 4; t++) {
                int row = row0 + t;
                float v = acc[i][j][t] + bv[j];
                if (RESM == 1) v += b2f(res16[(size_t)row * N + col]);
                if (RESM == 2) v += res32[(size_t)row * N + col];
                if (RELU) v = fmaxf(v, 0.f);
                if (OSPLIT) {
                    int l = row / Q_;
                    int pix = row - l * Q_;
                    int h = col >> 5, dd = col & 31;
                    Cout[(((size_t)l * NH_ + h) * (size_t)Q_ + pix) * HD_ + dd] = f2b(v);
                } else {
                    Cout[(size_t)row * N + col] = f2b(v);
                }
            }
        }
    }
}

// ---------------- fused softmax + bilinear sampling (ILP=2 + folded fp32 copy) ----------------
// v: [L, NH, Q_, HD] bf16 (head-split).  Each 32-lane group handles TWO (q,h) groups.
// Additionally each thread copies one float4 of passthrough output (csrc->cdst).
template<int L>
__global__ __launch_bounds__(256) void sample_kernel(
    const ushort_t* __restrict__ v,
    const ushort_t* __restrict__ off,  // [Q, NH*L*NP*2] bf16
    const ushort_t* __restrict__ aw,   // [Q, NH*L*NP] bf16
    const float*    __restrict__ ref,  // [Q, LC, 2] fp32
    ushort_t* __restrict__ outp,       // [Q, C] bf16
    const float4* __restrict__ csrc, float4* __restrict__ cdst, int cnum)
{
    const int tid = blockIdx.x * 256 + threadIdx.x;
    const bool do_copy = (tid < cnum);
    float4 cval;
    if (do_copy) cval = csrc[tid];

    constexpr int P = L * NP_;
    constexpr int HALFG = Q_ * NH_ / 2;
    const int g0 = tid >> 5;
    const int d = threadIdx.x & 31;

    int qq[2], hh[2];
    float wn[2][P];
    ushort_t offr[2][2 * P];
    float rx[2][L], ry[2][L];

    #pragma unroll
    for (int u = 0; u < 2; u++) {
        const int g = g0 + u * HALFG;
        const int q = g >> 3, h = g & 7;
        qq[u] = q; hh[u] = h;

        // attention-weight logits (vector load)
        ushort_t awr[P];
        const ushort_t* awp = aw + (size_t)q * (NH_ * P) + h * P;
        if (L == 2) {
            union { uint4 v4; ushort_t us[8]; } t; t.v4 = *(const uint4*)awp;
            #pragma unroll
            for (int i = 0; i < 8; i++) awr[i] = t.us[i];
        } else {
            union { uint2 v2; ushort_t us[4]; } t; t.v2 = *(const uint2*)awp;
            #pragma unroll
            for (int i = 0; i < 4; i++) awr[i] = t.us[i];
        }
        // offsets (vector load)
        const ushort_t* offp = off + (size_t)q * (NH_ * 2 * P) + h * 2 * P;
        if (L == 2) {
            union { uint4 v4; ushort_t us[8]; } t0, t1;
            t0.v4 = ((const uint4*)offp)[0];
            t1.v4 = ((const uint4*)offp)[1];
            #pragma unroll
            for (int i = 0; i < 8; i++) { offr[u][i] = t0.us[i]; offr[u][8 + i] = t1.us[i]; }
        } else {
            union { uint4 v4; ushort_t us[8]; } t0;
            t0.v4 = *(const uint4*)offp;
            #pragma unroll
            for (int i = 0; i < 8; i++) offr[u][i] = t0.us[i];
        }
        // softmax (pre-normalized weights)
        float w[P]; float mx = -1e30f;
        #pragma unroll
        for (int i = 0; i < P; i++) { w[i] = b2f(awr[i]); mx = fmaxf(mx, w[i]); }
        float s = 0.f;
        #pragma unroll
        for (int i = 0; i < P; i++) { w[i] = __expf(w[i] - mx); s += w[i]; }
        float inv = 1.f / s;
        #pragma unroll
        for (int i = 0; i < P; i++) wn[u][i] = w[i] * inv;
        // reference points
        if (L == 2) {
            float4 r4 = *(const float4*)(ref + (size_t)q * 4);
            rx[u][0] = r4.x * (float)HW_ - 0.5f; ry[u][0] = r4.y * (float)HW_ - 0.5f;
            rx[u][1] = r4.z * (float)HW_ - 0.5f; ry[u][1] = r4.w * (float)HW_ - 0.5f;
        } else {
            float2 r2 = *(const float2*)(ref + (size_t)q * 4);
            rx[u][0] = r2.x * (float)HW_ - 0.5f; ry[u][0] = r2.y * (float)HW_ - 0.5f;
        }
    }

    float acc[2] = {0.f, 0.f};
    #pragma unroll
    for (int l = 0; l < L; l++) {
        #pragma unroll
        for (int p = 0; p < NP_; p++) {
            const int ip = l * NP_ + p;
            float c[2][4], tx[2], ty[2];
            #pragma unroll
            for (int u = 0; u < 2; u++) {
                float x = rx[u][l] + b2f(offr[u][ip * 2 + 0]);
                float y = ry[u][l] + b2f(offr[u][ip * 2 + 1]);
                x = fminf(fmaxf(x, -1e4f), 1e4f);
                y = fminf(fmaxf(y, -1e4f), 1e4f);
                float xf = floorf(x), yf = floorf(y);
                tx[u] = x - xf; ty[u] = y - yf;
                int x0 = (int)xf, y0 = (int)yf;
                const ushort_t* base = v + ((size_t)(l * NH_ + hh[u]) * (size_t)Q_) * HD_ + d;
                int xc, yc; bool val;
                #define CORNER(OUT, XI, YI) \
                    xc = (XI) < 0 ? 0 : ((XI) > HW_-1 ? HW_-1 : (XI)); \
                    yc = (YI) < 0 ? 0 : ((YI) > HW_-1 ? HW_-1 : (YI)); \
                    val = ((XI) >= 0) & ((XI) < HW_) & ((YI) >= 0) & ((YI) < HW_); \
                    OUT = val ? b2f(base[(size_t)(yc * HW_ + xc) * HD_]) : 0.f;
                CORNER(c[u][0], x0,     y0)
                CORNER(c[u][1], x0 + 1, y0)
                CORNER(c[u][2], x0,     y0 + 1)
                CORNER(c[u][3], x0 + 1, y0 + 1)
                #undef CORNER
            }
            #pragma unroll
            for (int u = 0; u < 2; u++) {
                float bil = (c[u][0] * (1.f - tx[u]) + c[u][1] * tx[u]) * (1.f - ty[u])
                          + (c[u][2] * (1.f - tx[u]) + c[u][3] * tx[u]) * ty[u];
                acc[u] += bil * wn[u][ip];
            }
        }
    }
    outp[(size_t)qq[0] * C_ + hh[0] * HD_ + d] = f2b(acc[0]);
    outp[(size_t)qq[1] * C_ + hh[1] * HD_ + d] = f2b(acc[1]);
    if (do_copy) cdst[tid] = cval;
}

// ---------------- LayerNorm (wave per row of 256) ----------------
template<bool OUT32>
__global__ __launch_bounds__(256) void ln_kernel(
    const ushort_t* __restrict__ x, const float* __restrict__ g,
    const float* __restrict__ b, ushort_t* __restrict__ y16,
    float* __restrict__ y32,
    const float* __restrict__ qpos, ushort_t* __restrict__ y2)
{
    const int lane = threadIdx.x & 63;
    const int wave = threadIdx.x >> 6;
    const size_t row = (size_t)blockIdx.x * 4 + wave;
    const size_t base = row * C_ + lane * 4;

    uint2 xv = *(const uint2*)(x + base);
    float f0 = b2f((ushort_t)(xv.x & 0xFFFF)), f1 = b2f((ushort_t)(xv.x >> 16));
    float f2 = b2f((ushort_t)(xv.y & 0xFFFF)), f3 = b2f((ushort_t)(xv.y >> 16));
    float s  = f0 + f1 + f2 + f3;
    float sq = f0 * f0 + f1 * f1 + f2 * f2 + f3 * f3;
    #pragma unroll
    for (int m = 1; m < 64; m <<= 1) { s += __shfl_xor(s, m, 64); sq += __shfl_xor(sq, m, 64); }
    float mean = s * (1.f / 256.f);
    float var  = sq * (1.f / 256.f) - mean * mean;
    float rinv = rsqrtf(fmaxf(var, 0.f) + 1e-5f);

    float4 gv = *(const float4*)(g + lane * 4);
    float4 bv = *(const float4*)(b + lane * 4);
    float o0 = (f0 - mean) * rinv * gv.x + bv.x;
    float o1 = (f1 - mean) * rinv * gv.y + bv.y;
    float o2 = (f2 - mean) * rinv * gv.z + bv.z;
    float o3 = (f3 - mean) * rinv * gv.w + bv.w;

    if (OUT32) {
        float4 o; o.x = o0; o.y = o1; o.z = o2; o.w = o3;
        *(float4*)(y32 + base) = o;
    } else {
        uint2 ov; ov.x = pack2(o0, o1); ov.y = pack2(o2, o3);
        *(uint2*)(y16 + base) = ov;
    }

    if (y2) {
        float4 pv = *(const float4*)(qpos + base);
        uint2 o2v;
        o2v.x = pack2(o0 + pv.x, o1 + pv.y);
        o2v.y = pack2(o2 + pv.z, o3 + pv.w);
        *(uint2*)(y2 + base) = o2v;
    }
}

// ---------------- host ----------------
extern "C" void kernel_launch(void* const* d_in, const int* in_sizes, int n_in,
                              void* d_out, int out_size, void* d_ws, size_t ws_size,
                              hipStream_t stream)
{
    const float* query = (const float*)d_in[0];
    const float* qpos  = (const float*)d_in[1];
    const float* value = (const float*)d_in[2];
    const float* ref   = (const float*)d_in[3];
    const int*   ss    = (const int*)d_in[4];
    const float* sa_off_w = (const float*)d_in[5];
    const float* sa_off_b = (const float*)d_in[6];
    const float* sa_aw_w  = (const float*)d_in[7];
    const float* sa_aw_b  = (const float*)d_in[8];
    const float* sa_vp_w  = (const float*)d_in[9];
    const float* sa_vp_b  = (const float*)d_in[10];
    const float* sa_op_w  = (const float*)d_in[11];
    const float* sa_op_b  = (const float*)d_in[12];
    const float* ca_off_w = (const float*)d_in[13];
    const float* ca_off_b = (const float*)d_in[14];
    const float* ca_aw_w  = (const float*)d_in[15];
    const float* ca_aw_b  = (const float*)d_in[16];
    const float* ca_vp_w  = (const float*)d_in[17];
    const float* ca_vp_b  = (const float*)d_in[18];
    const float* ca_op_w  = (const float*)d_in[19];
    const float* ca_op_b  = (const float*)d_in[20];
    const float* ffn_w1   = (const float*)d_in[21];
    const float* ffn_b1   = (const float*)d_in[22];
    const float* ffn_w2   = (const float*)d_in[23];
    const float* ffn_b2   = (const float*)d_in[24];
    const float* ln1_g = (const float*)d_in[25];
    const float* ln1_b = (const float*)d_in[26];
    const float* ln2_g = (const float*)d_in[27];
    const float* ln2_b = (const float*)d_in[28];
    const float* ln3_g = (const float*)d_in[29];
    const float* ln3_b = (const float*)d_in[30];

    // ---- final output layout (fp32) ----
    float* outf    = (float*)d_out;
    float* out_q   = outf;                            // [Q,C]
    float* out_qp  = outf + QC;                       // [Q,C]
    float* out_val = outf + 2 * (size_t)QC;           // [2Q,C]
    float* out_ref = outf + 4 * (size_t)QC;           // [Q,LC,2]
    float* out_ss  = outf + 4 * (size_t)QC + REFN;    // [4]

    // ---- d_out doubles as bf16 body scratch (all dead before final writes) ----
    ushort_t* dsc    = (ushort_t*)d_out;
    ushort_t* vbuf   = dsc;                           // [L,NH,Q,HD] bf16, bytes [0, 26.2M)
    ushort_t* tmp    = dsc + 2 * (size_t)QC;          // bytes [26.2M, 39.3M)
    ushort_t* offb   = dsc + 3 * (size_t)QC;          // Q*128
    ushort_t* awb    = dsc + 3 * (size_t)QC + (size_t)Q_ * 128;  // Q*64
    ushort_t* hidden = dsc;                           // [Q,1024] bf16: bytes [0, 52.4M)

    // ---- workspace: ~42.8 MB bf16 ----
    char* base = (char*)d_ws;
    size_t offbyte = 0;
    auto alloc = [&](size_t elems) -> ushort_t* {
        ushort_t* p = (ushort_t*)(base + offbyte);
        offbyte += ((elems * 2 + 255) / 256) * 256;
        return p;
    };
    ushort_t* wt_sa_off = alloc(256 * 64);
    ushort_t* wt_sa_aw  = alloc(256 * 32);
    ushort_t* wt_sa_vp  = alloc(256 * 256);
    ushort_t* wt_sa_op  = alloc(256 * 256);
    ushort_t* wt_ca_off = alloc(256 * 128);
    ushort_t* wt_ca_aw  = alloc(256 * 64);
    ushort_t* wt_ca_vp  = alloc(256 * 256);
    ushort_t* wt_ca_op  = alloc(256 * 256);
    ushort_t* wt_ffn1   = alloc(256 * 1024);
    ushort_t* wt_ffn2   = alloc(1024 * 256);
    ushort_t* qpq  = alloc(QC);     // bf16(q+pos), then bf16(q1+pos)
    ushort_t* attn = alloc(QC);     // sampled attention out; later q2 (LN2 out)
    ushort_t* q1   = alloc(QC);     // LN1 out; later FFN2 out
    ushort_t* q2   = attn;          // LN2 out overlays dead attn

    TAll td;
    const float* srcs[10] = {sa_off_w, sa_aw_w, sa_vp_w, sa_op_w, ca_off_w,
                             ca_aw_w, ca_vp_w, ca_op_w, ffn_w1, ffn_w2};
    ushort_t* dsts[10] = {wt_sa_off, wt_sa_aw, wt_sa_vp, wt_sa_op, wt_ca_off,
                          wt_ca_aw, wt_ca_vp, wt_ca_op, wt_ffn1, wt_ffn2};
    int Ks[10] = {256, 256, 256, 256, 256, 256, 256, 256, 256, 1024};
    int Ns[10] = {64, 32, 256, 256, 128, 64, 256, 256, 1024, 256};
    for (int m = 0; m < 10; m++) { td.t[m] = {srcs[m], dsts[m], Ks[m], Ns[m]}; }

    // 1. prologue
    prologue_kernel<<<(PRO_TOTAL + 255) / 256, 256, 0, stream>>>(query, qpos, qpq, td);

    // ---- self-attention (L=1, value = raw fp32 query) ----
    gemm_bf16<4, false, 0, true, 1><<<dim3(Q_ / 256, 4), 256, 0, stream>>>(
        nullptr, query, wt_sa_vp, sa_vp_b, nullptr, nullptr, vbuf, Q_, 256, 256);
    gemm_bf16<4, false, 0, false, 0><<<dim3(Q_ / 256, 1), 256, 0, stream>>>(
        qpq, nullptr, wt_sa_off, sa_off_b, nullptr, nullptr, offb, Q_, 64, 256);
    gemm_bf16<2, false, 0, false, 0><<<dim3(Q_ / 256, 1), 256, 0, stream>>>(
        qpq, nullptr, wt_sa_aw, sa_aw_b, nullptr, nullptr, awb, Q_, 32, 256);
    // SA sample (ILP2) + folded out_ref copy
    sample_kernel<1><<<(Q_ * NH_) / 16, 256, 0, stream>>>(
        vbuf, offb, awb, ref, attn,
        (const float4*)ref, (float4*)out_ref, REFN / 4);
    gemm_bf16<4, false, 2, false, 0><<<dim3(Q_ / 256, 4), 256, 0, stream>>>(
        attn, nullptr, wt_sa_op, sa_op_b, nullptr, query, tmp, Q_, 256, 256);
    ln_kernel<false><<<Q_ / 4, 256, 0, stream>>>(tmp, ln1_g, ln1_b, q1, nullptr, qpos, qpq);

    // ---- cross-attention (L=2, value = raw fp32 value) ----
    gemm_bf16<4, false, 0, true, 1><<<dim3(2 * Q_ / 256, 4), 256, 0, stream>>>(
        nullptr, value, wt_ca_vp, ca_vp_b, nullptr, nullptr, vbuf, 2 * Q_, 256, 256);
    gemm_bf16<4, false, 0, false, 0><<<dim3(Q_ / 256, 2), 256, 0, stream>>>(
        qpq, nullptr, wt_ca_off, ca_off_b, nullptr, nullptr, offb, Q_, 128, 256);
    gemm_bf16<4, false, 0, false, 0><<<dim3(Q_ / 256, 1), 256, 0, stream>>>(
        qpq, nullptr, wt_ca_aw, ca_aw_b, nullptr, nullptr, awb, Q_, 64, 256);
    // CA sample (ILP2) + folded out_val copy (grid*256 == VC/4 exactly)
    sample_kernel<2><<<(Q_ * NH_) / 16, 256, 0, stream>>>(
        vbuf, offb, awb, ref, attn,
        (const float4*)value, (float4*)out_val, VC / 4);
    gemm_bf16<4, false, 1, false, 0><<<dim3(Q_ / 256, 4), 256, 0, stream>>>(
        attn, nullptr, wt_ca_op, ca_op_b, q1, nullptr, tmp, Q_, 256, 256);
    ln_kernel<false><<<Q_ / 4, 256, 0, stream>>>(tmp, ln2_g, ln2_b, q2, nullptr, nullptr, nullptr);

    // ---- FFN ----
    gemm_bf16<4, true, 0, false, 0><<<dim3(Q_ / 256, 16), 256, 0, stream>>>(
        q2, nullptr, wt_ffn1, ffn_b1, nullptr, nullptr, hidden, Q_, 1024, 256);
    gemm_bf16<4, false, 1, false, 0><<<dim3(Q_ / 256, 4), 256, 0, stream>>>(
        hidden, nullptr, wt_ffn2, ffn_b2, q2, nullptr, q1, Q_, 256, 1024);
    // LN3 -> fp32 final output (overlays dead hidden region)
    ln_kernel<true><<<Q_ / 4, 256, 0, stream>>>(q1, ln3_g, ln3_b, nullptr, out_q, nullptr, nullptr);

    // ---- remaining passthroughs ----
    hipMemcpyAsync(out_qp, qpos, (size_t)QC * 4, hipMemcpyDeviceToDevice, stream);
    ss_kernel<<<1, 64, 0, stream>>>(ss, out_ss);

    (void)in_sizes; (void)n_in; (void)out_size; (void)ws_size;
}